// Round 7
// baseline (2712.260 us; speedup 1.0000x reference)
//
#include <hip/hip_runtime.h>
#include <hip/hip_bf16.h>
#include <stdint.h>

typedef __bf16 bf16x8 __attribute__((ext_vector_type(8)));
typedef float f32x4 __attribute__((ext_vector_type(4)));
typedef unsigned short u16;
typedef unsigned short u16x4 __attribute__((ext_vector_type(4)));
typedef unsigned int u32;
typedef unsigned long long u64;

#define B_  64
#define S_  256
#define I_  1024
#define H_  1024
#define NG  4096      /* 4*H */
#define M_  16384     /* S*B */

using gvoid_p = const __attribute__((address_space(1))) void*;
using lvoid_p = __attribute__((address_space(3))) void*;

__device__ __forceinline__ void gl_lds16(const void* g, void* l) {
  __builtin_amdgcn_global_load_lds((gvoid_p)g, (lvoid_p)l, 16, 0, 0);
}

__device__ __forceinline__ u16 f2bf(float f) {
  __hip_bfloat16 h = __float2bfloat16(f);
  union { __hip_bfloat16 h; u16 u; } c; c.h = h; return c.u;
}
__device__ __forceinline__ float bf2f(u16 u) {
  union { unsigned u; float f; } c; c.u = ((unsigned)u) << 16; return c.f;
}

// 8B LLC-coherent load (relaxed agent atomic). Also used for W pinning:
// atomics are NOT rematerializable, so values loaded this way stay resident.
__device__ __forceinline__ u64 ld8(const u64* p) {
  return __hip_atomic_load(p, __ATOMIC_RELAXED, __HIP_MEMORY_SCOPE_AGENT);
}

// ---- fp32 -> bf16 converts -------------------------------------------------
__global__ void cvt_x(const float* __restrict__ x, u16* __restrict__ xb) {
  int bid = blockIdx.x;            // = s*64 + b
  int b = bid & 63, s = bid >> 6;
  int t = threadIdx.x;
  float4 v = ((const float4*)(x + (size_t)b * (S_ * I_) + (size_t)s * I_))[t];
  u16x4 o;
  o[0] = f2bf(v.x); o[1] = f2bf(v.y); o[2] = f2bf(v.z); o[3] = f2bf(v.w);
  ((u16x4*)(xb + (size_t)bid * I_))[t] = o;
}

__global__ void cvt_w(const float* __restrict__ w, u16* __restrict__ wb) {
  size_t i = ((size_t)blockIdx.x * 256 + threadIdx.x) * 4;
  float4 v = *(const float4*)(w + i);
  u16x4 o;
  o[0] = f2bf(v.x); o[1] = f2bf(v.y); o[2] = f2bf(v.z); o[3] = f2bf(v.w);
  *(u16x4*)(wb + i) = o;
}

// w_i row (g*1024+c) -> permuted row (c*4+g): gemm emits gx with the 4 gates
// of one column adjacent (one 8B load/lane/step in the recurrence).
__global__ void cvt_w_perm(const float* __restrict__ w, u16* __restrict__ wb) {
  const int r = blockIdx.x;                 // source row 0..4095
  const int g = r >> 10, c = r & 1023;
  const int rp = c * 4 + g;
  float4 v = ((const float4*)(w + (size_t)r * I_))[threadIdx.x];
  u16x4 o;
  o[0] = f2bf(v.x); o[1] = f2bf(v.y); o[2] = f2bf(v.z); o[3] = f2bf(v.w);
  ((u16x4*)(wb + (size_t)rp * I_))[threadIdx.x] = o;
}

// ---- big input GEMM: gx[16384][4096] = X * WiP^T (row-major C) -------------
__global__ __launch_bounds__(256) void gemm_bt(const u16* __restrict__ A,
                                               const u16* __restrict__ BT,
                                               u16* __restrict__ C) {
  __shared__ u16 As[128 * 32];
  __shared__ u16 Bs[128 * 32];
  const int tid  = threadIdx.x;
  const int lane = tid & 63;
  const int wv   = tid >> 6;
  const int wm   = wv & 1, wn = wv >> 1;
  const int quad = lane >> 4, l16 = lane & 15;
  const int m0 = blockIdx.y * 128;
  const int n0 = blockIdx.x * 128;

  const int c0i = tid, c1i = tid + 256;
  const int ar0 = c0i >> 2, ak0 = (c0i & 3) * 8;
  const int ar1 = c1i >> 2, ak1 = (c1i & 3) * 8;

  f32x4 acc[4][4] = {};

  for (int kt = 0; kt < 32; ++kt) {
    const int k0 = kt * 32;
    __syncthreads();
    gl_lds16(A + (size_t)(m0 + ar0) * I_ + k0 + ak0, &As[c0i * 8]);
    gl_lds16(A + (size_t)(m0 + ar1) * I_ + k0 + ak1, &As[c1i * 8]);
    gl_lds16(BT + (size_t)(n0 + ar0) * I_ + k0 + ak0, &Bs[c0i * 8]);
    gl_lds16(BT + (size_t)(n0 + ar1) * I_ + k0 + ak1, &Bs[c1i * 8]);
    __syncthreads();

    bf16x8 af[4], bfr[4];
#pragma unroll
    for (int mi = 0; mi < 4; ++mi)
      af[mi] = *(const bf16x8*)&As[(wm * 64 + mi * 16 + l16) * 32 + quad * 8];
#pragma unroll
    for (int ni = 0; ni < 4; ++ni)
      bfr[ni] = *(const bf16x8*)&Bs[(wn * 64 + ni * 16 + l16) * 32 + quad * 8];
#pragma unroll
    for (int mi = 0; mi < 4; ++mi)
#pragma unroll
      for (int ni = 0; ni < 4; ++ni)
        acc[mi][ni] = __builtin_amdgcn_mfma_f32_16x16x32_bf16(af[mi], bfr[ni], acc[mi][ni], 0, 0, 0);
  }

#pragma unroll
  for (int mi = 0; mi < 4; ++mi)
#pragma unroll
    for (int ni = 0; ni < 4; ++ni) {
      const int col = n0 + wn * 64 + ni * 16 + l16;
#pragma unroll
      for (int r = 0; r < 4; ++r) {
        const int row = m0 + wm * 64 + mi * 16 + quad * 4 + r;
        C[(size_t)row * NG + col] = f2bf(acc[mi][ni][r]);
      }
    }
}

// ---- persistent recurrent kernel -------------------------------------------
// Round-7 = round-2's PROVEN flag protocol x round-3/5's PROVEN 128x512
// launch envelope. Halving block count (vs r2) halves the per-step h stage
// fan-out: 128 blocks x 32KB = 4MB/step LLC reads (was 8MB) — the stage was
// r2's largest step term since per-block read cost is independent of how
// many cols the block computes.
//
// 128 blocks = 4 batch-quarters (q = blk&3) x 32 col-groups (cg = blk>>2).
// 8 waves; wave v owns h-cols [cg*32 + v*4, +4). W_h slice pinned in 128
// regs/wave via atomic loads. A-tile rows = {4 gates x 4 cols} so each
// lane's f32x4 acc holds i,f,g,o of ONE (row,col): lane-local cell update.
//
// PER-WAVE flags (the one new element): each wave publishes its h slice,
// wave-local vmcnt(0), then stores flags[q][cg][v] = s+2. Deletes the
// block-wide drain barrier (r2's barrier #2) -> 1 barrier/step. Overwrite
// safety (depth-2 hbuf): P publishes h(s+1) only after staging h(s), which
// required every wave's flag >= s+1, which each wave set only after its
// vmcnt(0) drained its h(s) store AND its h(s-1) stage loads.
// Round-4/6 lesson: exactly-full co-residency launches silently fail —
// this shape (128 blk, 512 thr, 64KB LDS, bounds (512,2)) is r3/r5-proven.
__global__ __launch_bounds__(512, 2) void lstm_rec(
    const u16* __restrict__ whb,     // [4096][1024] bf16 (gate-major rows)
    const u16* __restrict__ gxp,     // [(s*64+b)][c*4+g] bf16 (permuted cols)
    const float* __restrict__ b_i, const float* __restrict__ b_h,
    const float* __restrict__ h0, const float* __restrict__ c0,
    u16* hbuf,                       // [2][64][1024] bf16 (double buffer)
    u32* flags,                      // [4][32][8]; value = s+2 when h(s+1) out
    float* __restrict__ out) {       // hidden[64][256][1024], hN, cN
  const int tid = threadIdx.x, lane = tid & 63, v = tid >> 6;  // v 0..7
  const int quad = lane >> 4, l16 = lane & 15;
  const int blk = blockIdx.x;
  const int q = blk & 3, cg = blk >> 2;    // cg 0..31
  const int colbase = cg * 32 + v * 4;
  const int row = q * 16 + l16;            // batch row
  const int col = colbase + quad;          // h column

  __shared__ __align__(16) u16 hs[2 * 16 * 1024];  // 64 KB double-buffered

  float cst = c0[(size_t)row * H_ + col];
  float hl  = h0[(size_t)row * H_ + col];

  // publish h0 (pack 4 cols -> u64 in quad0 lanes), wave drain, flag = 1
  {
    float ha = __shfl_down(hl, 16);
    unsigned lo = (unsigned)f2bf(hl) | ((unsigned)f2bf(ha) << 16);
    unsigned p2 = __shfl_down(lo, 32);
    if (quad == 0) {
      u64 pp = (u64)lo | ((u64)p2 << 32);
      __hip_atomic_store((u64*)(hbuf + (size_t)row * H_ + colbase), pp,
                         __ATOMIC_RELAXED, __HIP_MEMORY_SCOPE_AGENT);
    }
    asm volatile("s_waitcnt vmcnt(0)" ::: "memory");
    if (lane == 0)
      __hip_atomic_store(&flags[(q * 32 + cg) * 8 + v], 1u,
                         __ATOMIC_RELAXED, __HIP_MEMORY_SCOPE_AGENT);
  }

  f32x4 bias;
#pragma unroll
  for (int r = 0; r < 4; ++r)
    bias[r] = b_i[r * H_ + col] + b_h[r * H_ + col];

  // W_h fragments -> registers (atomic loads: compiler cannot remat them).
  // A-row m=l16 -> (gate = l16&3, col off = l16>>2); D rows m=quad*4+r give
  // (gate=r, col=colbase+quad).
  const int wrow = (l16 & 3) * H_ + colbase + (l16 >> 2);
  bf16x8 wf[32];
#pragma unroll
  for (int kt = 0; kt < 32; ++kt) {
    const u64* wp = (const u64*)(whb + (size_t)wrow * H_ + kt * 32 + quad * 8);
    union { u64 u[2]; bf16x8 v; } c;
    c.u[0] = ld8(wp);
    c.u[1] = ld8(wp + 1);
    wf[kt] = c.v;
  }

  const char* hsb = (const char*)hs;
  const int swz = (l16 & 7) << 4;          // XOR swizzle (16B granules)

#pragma unroll 1
  for (int s = 0; s < S_; ++s) {
    // gx early (plain load, L2/LLC-resident)
    u16x4 gx4 = *(const u16x4*)(gxp + (size_t)(s * 64 + row) * NG + col * 4);

    // every wave polls its quarter's 256 per-wave flags (4 u32 per lane)
    {
      const u64* f8 = (const u64*)(flags + q * 256);
      const u32 tgt = (u32)(s + 1);
      while (1) {
        u64 a = ld8(f8 + lane * 2);
        u64 b = ld8(f8 + lane * 2 + 1);
        bool ok = ((u32)a >= tgt) & ((u32)(a >> 32) >= tgt)
                & ((u32)b >= tgt) & ((u32)(b >> 32) >= tgt);
        if (__all((int)ok)) break;
        __builtin_amdgcn_s_sleep(1);
      }
    }

    // stage h(s): wave v stages rows 2v, 2v+1 (4KB) -> swizzled LDS
    {
      const u64* src = (const u64*)(hbuf + (size_t)(s & 1) * (B_ * H_)
                                         + (size_t)(q * 16 + v * 2) * H_);
      u64 stg[8];
#pragma unroll
      for (int i = 0; i < 2; ++i)
#pragma unroll
        for (int j = 0; j < 4; ++j)
          stg[i * 4 + j] = ld8(src + (size_t)i * 256 + j * 64 + lane);
      char* dst = (char*)hs + (size_t)(s & 1) * 32768;
#pragma unroll
      for (int i = 0; i < 2; ++i) {
        const int r = v * 2 + i;
#pragma unroll
        for (int j = 0; j < 4; ++j) {
          const int u = j * 64 + lane;
          *(u64*)(dst + (size_t)r * 2048 + ((u * 8) ^ ((r & 7) << 4))) =
              stg[i * 4 + j];
        }
      }
    }
    __syncthreads();   // the ONLY barrier per step: stage visible to all

    // GEMV: acc[r] accumulates gate r at (row, col); 32 MFMAs, 4-way ILP
    f32x4 acc[4] = {};
#pragma unroll
    for (int kt = 0; kt < 32; ++kt) {
      bf16x8 bv = *(const bf16x8*)(hsb + (size_t)(s & 1) * 32768
                                   + l16 * 2048 + ((kt * 64 + quad * 16) ^ swz));
      acc[kt & 3] = __builtin_amdgcn_mfma_f32_16x16x32_bf16(wf[kt], bv, acc[kt & 3], 0, 0, 0);
    }

    f32x4 g4;
#pragma unroll
    for (int r = 0; r < 4; ++r)
      g4[r] = acc[0][r] + acc[1][r] + acc[2][r] + acc[3][r]
            + bias[r] + bf2f(gx4[r]);

    float iv = 1.f / (1.f + __expf(-g4[0]));
    float fv = 1.f / (1.f + __expf(-g4[1]));
    float gz = fminf(fmaxf(g4[2], -15.f), 15.f);
    float eg = __expf(2.f * gz);
    float gv = (eg - 1.f) / (eg + 1.f);
    float ov = 1.f / (1.f + __expf(-g4[3]));
    float cn = fv * cst + iv * gv;
    cst = cn;
    float cc = fminf(fmaxf(cn, -15.f), 15.f);
    float ec = __expf(2.f * cc);
    hl = ov * ((ec - 1.f) / (ec + 1.f));

    // publish h(s+1), wave-local drain, per-wave flag; out AFTER flag
    float ha = __shfl_down(hl, 16);                  // col+1
    unsigned lo = (unsigned)f2bf(hl) | ((unsigned)f2bf(ha) << 16);
    unsigned p2 = __shfl_down(lo, 32);               // cols +2,+3
    float o2 = __shfl_down(hl, 32);
    float o3 = __shfl_down(ha, 32);
    if (quad == 0) {
      u64 pp = (u64)lo | ((u64)p2 << 32);
      __hip_atomic_store(
          (u64*)(hbuf + (size_t)(((s + 1) & 1)) * (B_ * H_)
                      + (size_t)row * H_ + colbase),
          pp, __ATOMIC_RELAXED, __HIP_MEMORY_SCOPE_AGENT);
    }
    asm volatile("s_waitcnt vmcnt(0)" ::: "memory");
    if (lane == 0)
      __hip_atomic_store(&flags[(q * 32 + cg) * 8 + v], (u32)(s + 2),
                         __ATOMIC_RELAXED, __HIP_MEMORY_SCOPE_AGENT);
    if (quad == 0) {
      f32x4 ovv = { hl, ha, o2, o3 };
      __builtin_nontemporal_store(ovv,
          (f32x4*)(out + ((size_t)row * S_ + s) * H_ + colbase));
    }
  }

  // final hN, cN
  {
    const size_t base = (size_t)B_ * S_ * H_;
    out[base + (size_t)row * H_ + col] = hl;
    out[base + (size_t)B_ * H_ + (size_t)row * H_ + col] = cst;
  }
}

// ---- launch ----------------------------------------------------------------
extern "C" void kernel_launch(void* const* d_in, const int* in_sizes, int n_in,
                              void* d_out, int out_size, void* d_ws, size_t ws_size,
                              hipStream_t stream) {
  const float* x  = (const float*)d_in[0];
  const float* h0 = (const float*)d_in[1];
  const float* c0 = (const float*)d_in[2];
  const float* wi = (const float*)d_in[3];
  const float* wh = (const float*)d_in[4];
  const float* bi = (const float*)d_in[5];
  const float* bh = (const float*)d_in[6];
  float* out = (float*)d_out;

  char* ws = (char*)d_ws;
  u16* xb   = (u16*)(ws);                   //  33,554,432 B (dead after gemm_bt)
  u16* wib  = (u16*)(ws + 33554432);        //   8,388,608 B (permuted W_i)
  u16* whb  = (u16*)(ws + 41943040);        //   8,388,608 B
  u16* gxp  = (u16*)(ws + 50331648);        // 134,217,728 B
  u16* hbuf = (u16*)(ws + 184549376);       //     262,144 B (double buffer)
  u32* flags = (u32*)(ws + 184811520);      //       4,096 B

  cvt_x<<<M_, 256, 0, stream>>>(x, xb);
  cvt_w_perm<<<NG, 256, 0, stream>>>(wi, wib);
  cvt_w<<<4096, 256, 0, stream>>>(wh, whb);
  gemm_bt<<<dim3(NG / 128, M_ / 128), 256, 0, stream>>>(xb, wib, gxp);
  // zero flags AFTER gemm_bt (stream-ordered); kills stale values on replay
  (void)hipMemsetAsync(flags, 0, 4096, stream);

  void* args[] = { &whb, &gxp, &bi, &bh, &h0, &c0, &hbuf, &flags, &out };
  (void)hipLaunchCooperativeKernel((void*)lstm_rec, dim3(128), dim3(512), args, 0, stream);
}

// Round 8
// 1269.937 us; speedup vs baseline: 2.1357x; 2.1357x over previous
//
#include <hip/hip_runtime.h>
#include <hip/hip_bf16.h>
#include <stdint.h>

typedef __bf16 bf16x8 __attribute__((ext_vector_type(8)));
typedef float f32x4 __attribute__((ext_vector_type(4)));
typedef unsigned short u16;
typedef unsigned short u16x4 __attribute__((ext_vector_type(4)));
typedef unsigned int u32;
typedef unsigned int u32x4 __attribute__((ext_vector_type(4)));
typedef unsigned long long u64;

#define B_  64
#define S_  256
#define I_  1024
#define H_  1024
#define NG  4096      /* 4*H */
#define M_  16384     /* S*B */

using gvoid_p = const __attribute__((address_space(1))) void*;
using lvoid_p = __attribute__((address_space(3))) void*;

__device__ __forceinline__ void gl_lds16(const void* g, void* l) {
  __builtin_amdgcn_global_load_lds((gvoid_p)g, (lvoid_p)l, 16, 0, 0);
}

__device__ __forceinline__ u16 f2bf(float f) {
  __hip_bfloat16 h = __float2bfloat16(f);
  union { __hip_bfloat16 h; u16 u; } c; c.h = h; return c.u;
}
__device__ __forceinline__ float bf2f(u16 u) {
  union { unsigned u; float f; } c; c.u = ((unsigned)u) << 16; return c.f;
}

// 8B LLC-coherent load (relaxed agent atomic). Also used for W pinning:
// atomics are NOT rematerializable, so values loaded this way stay resident.
__device__ __forceinline__ u64 ld8(const u64* p) {
  return __hip_atomic_load(p, __ATOMIC_RELAXED, __HIP_MEMORY_SCOPE_AGENT);
}

// ---- fp32 -> bf16 converts -------------------------------------------------
__global__ void cvt_x(const float* __restrict__ x, u16* __restrict__ xb) {
  int bid = blockIdx.x;            // = s*64 + b
  int b = bid & 63, s = bid >> 6;
  int t = threadIdx.x;
  float4 v = ((const float4*)(x + (size_t)b * (S_ * I_) + (size_t)s * I_))[t];
  u16x4 o;
  o[0] = f2bf(v.x); o[1] = f2bf(v.y); o[2] = f2bf(v.z); o[3] = f2bf(v.w);
  ((u16x4*)(xb + (size_t)bid * I_))[t] = o;
}

__global__ void cvt_w(const float* __restrict__ w, u16* __restrict__ wb) {
  size_t i = ((size_t)blockIdx.x * 256 + threadIdx.x) * 4;
  float4 v = *(const float4*)(w + i);
  u16x4 o;
  o[0] = f2bf(v.x); o[1] = f2bf(v.y); o[2] = f2bf(v.z); o[3] = f2bf(v.w);
  *(u16x4*)(wb + i) = o;
}

// w_i row (g*1024+c) -> permuted row (c*4+g): gemm emits gx with the 4 gates
// of one column adjacent (one 8B load/lane/step in the recurrence).
__global__ void cvt_w_perm(const float* __restrict__ w, u16* __restrict__ wb) {
  const int r = blockIdx.x;                 // source row 0..4095
  const int g = r >> 10, c = r & 1023;
  const int rp = c * 4 + g;
  float4 v = ((const float4*)(w + (size_t)r * I_))[threadIdx.x];
  u16x4 o;
  o[0] = f2bf(v.x); o[1] = f2bf(v.y); o[2] = f2bf(v.z); o[3] = f2bf(v.w);
  ((u16x4*)(wb + (size_t)rp * I_))[threadIdx.x] = o;
}

// ---- big input GEMM: gx[16384][4096] = X * WiP^T (row-major C) -------------
__global__ __launch_bounds__(256) void gemm_bt(const u16* __restrict__ A,
                                               const u16* __restrict__ BT,
                                               u16* __restrict__ C) {
  __shared__ u16 As[128 * 32];
  __shared__ u16 Bs[128 * 32];
  const int tid  = threadIdx.x;
  const int lane = tid & 63;
  const int wv   = tid >> 6;
  const int wm   = wv & 1, wn = wv >> 1;
  const int quad = lane >> 4, l16 = lane & 15;
  const int m0 = blockIdx.y * 128;
  const int n0 = blockIdx.x * 128;

  const int c0i = tid, c1i = tid + 256;
  const int ar0 = c0i >> 2, ak0 = (c0i & 3) * 8;
  const int ar1 = c1i >> 2, ak1 = (c1i & 3) * 8;

  f32x4 acc[4][4] = {};

  for (int kt = 0; kt < 32; ++kt) {
    const int k0 = kt * 32;
    __syncthreads();
    gl_lds16(A + (size_t)(m0 + ar0) * I_ + k0 + ak0, &As[c0i * 8]);
    gl_lds16(A + (size_t)(m0 + ar1) * I_ + k0 + ak1, &As[c1i * 8]);
    gl_lds16(BT + (size_t)(n0 + ar0) * I_ + k0 + ak0, &Bs[c0i * 8]);
    gl_lds16(BT + (size_t)(n0 + ar1) * I_ + k0 + ak1, &Bs[c1i * 8]);
    __syncthreads();

    bf16x8 af[4], bfr[4];
#pragma unroll
    for (int mi = 0; mi < 4; ++mi)
      af[mi] = *(const bf16x8*)&As[(wm * 64 + mi * 16 + l16) * 32 + quad * 8];
#pragma unroll
    for (int ni = 0; ni < 4; ++ni)
      bfr[ni] = *(const bf16x8*)&Bs[(wn * 64 + ni * 16 + l16) * 32 + quad * 8];
#pragma unroll
    for (int mi = 0; mi < 4; ++mi)
#pragma unroll
      for (int ni = 0; ni < 4; ++ni)
        acc[mi][ni] = __builtin_amdgcn_mfma_f32_16x16x32_bf16(af[mi], bfr[ni], acc[mi][ni], 0, 0, 0);
  }

#pragma unroll
  for (int mi = 0; mi < 4; ++mi)
#pragma unroll
    for (int ni = 0; ni < 4; ++ni) {
      const int col = n0 + wn * 64 + ni * 16 + l16;
#pragma unroll
      for (int r = 0; r < 4; ++r) {
        const int row = m0 + wm * 64 + mi * 16 + quad * 4 + r;
        C[(size_t)row * NG + col] = f2bf(acc[mi][ni][r]);
      }
    }
}

// ---- persistent recurrent kernel -------------------------------------------
// ROUND-2 CHAMPION STRUCTURE (1130us measured), single delta: the stage
// loads are 16B device-coherent loads (global_load_dwordx4 sc0 sc1) instead
// of 2x8B agent atomics. Legal because once a quarter's flags are observed,
// hbuf data for that step is STABLE (written once) — only freshness is
// needed, and sc0 sc1 (system scope) is strictly stronger than the proven
// agent-atomic path. Halves stage issue + LLC request count (16 -> 8/lane).
// LDS placement is byte-identical (XOR swizzle keeps the two 8B halves of
// each 16B chunk contiguous).
//
// 256 blocks = 4 batch-quarters (q = blk&3) x 64 col-groups (cg4 = blk>>2).
// 4 waves/block; wave v owns h-cols [cg4*16 + v*4, +4). W_h slice pinned in
// 128 regs/wave via atomic loads. A-tile rows = {4 gates x 4 cols} so each
// lane's f32x4 acc holds i,f,g,o of ONE (row,col): lane-local cell update.
// Protocol per step: all-wave poll of 64 per-block flags -> stage -> barrier
// -> GEMV/act -> publish -> barrier (vmcnt drain) -> tid0 flag -> NT out.
__global__ __launch_bounds__(256, 1) void lstm_rec(
    const u16* __restrict__ whb,     // [4096][1024] bf16 (gate-major rows)
    const u16* __restrict__ gxp,     // [(s*64+b)][c*4+g] bf16 (permuted cols)
    const float* __restrict__ b_i, const float* __restrict__ b_h,
    const float* __restrict__ h0, const float* __restrict__ c0,
    u16* hbuf,                       // [2][64][1024] bf16 (double buffer)
    u32* flags,                      // [4][64]; flags[q][cg]=t+1 => h(t) ready
    float* __restrict__ out) {       // hidden[64][256][1024], hN, cN
  const int tid = threadIdx.x, lane = tid & 63, v = tid >> 6;  // v 0..3
  const int quad = lane >> 4, l16 = lane & 15;
  const int blk = blockIdx.x;
  const int q = blk & 3, cg4 = blk >> 2;
  const int colbase = cg4 * 16 + v * 4;
  const int row = q * 16 + l16;            // batch row
  const int col = colbase + quad;          // h column

  __shared__ __align__(16) u16 hs[16 * 1024];  // 32 KB staged h (swizzled)

  float cst = c0[(size_t)row * H_ + col];
  float hl  = h0[(size_t)row * H_ + col];

  // init: h0 slice -> hbuf[0], packed 4 cols -> u64 in quad0 lanes
  {
    float ha = __shfl_down(hl, 16);
    unsigned lo = (unsigned)f2bf(hl) | ((unsigned)f2bf(ha) << 16);
    unsigned p2 = __shfl_down(lo, 32);
    if (quad == 0) {
      u64 pp = (u64)lo | ((u64)p2 << 32);
      __hip_atomic_store((u64*)(hbuf + (size_t)row * H_ + colbase), pp,
                         __ATOMIC_RELAXED, __HIP_MEMORY_SCOPE_AGENT);
    }
  }
  __syncthreads();                   // vmcnt(0) drain: init h at LLC
  if (tid == 0)
    __hip_atomic_store(&flags[q * 64 + cg4], 1u,
                       __ATOMIC_RELAXED, __HIP_MEMORY_SCOPE_AGENT);

  f32x4 bias;
#pragma unroll
  for (int r = 0; r < 4; ++r)
    bias[r] = b_i[r * H_ + col] + b_h[r * H_ + col];

  // W_h fragments -> registers (atomic loads: compiler cannot remat them).
  // A-row m=l16 -> (gate = l16&3, col off = l16>>2); D rows m=quad*4+r give
  // (gate=r, col=colbase+quad).
  const int wrow = (l16 & 3) * H_ + colbase + (l16 >> 2);
  bf16x8 wf[32];
#pragma unroll
  for (int kt = 0; kt < 32; ++kt) {
    const u64* wp = (const u64*)(whb + (size_t)wrow * H_ + kt * 32 + quad * 8);
    union { u64 u[2]; bf16x8 v; } c;
    c.u[0] = ld8(wp);
    c.u[1] = ld8(wp + 1);
    wf[kt] = c.v;
  }

  const u32* fl = flags + q * 64;
  const char* hsb = (const char*)hs;
  const int swz = (l16 & 7) << 4;          // XOR swizzle (16B granules)

#pragma unroll 1
  for (int s = 0; s < S_; ++s) {
    // gx early (plain load, L2/LLC-resident)
    u16x4 gx4 = *(const u16x4*)(gxp + (size_t)(s * 64 + row) * NG + col * 4);

    // dataflow wait: ALL waves poll the quarter's 64 per-block flags
    {
      const unsigned tgt = (unsigned)(s + 1);
      while (1) {
        unsigned f = __hip_atomic_load(fl + lane, __ATOMIC_RELAXED, __HIP_MEMORY_SCOPE_AGENT);
        if (__all((int)(f >= tgt))) break;
        __builtin_amdgcn_s_sleep(1);
      }
    }

    // stage h(s): wave v stages rows v*4..v*4+3 (8KB) -> swizzled LDS.
    // 16B coherent loads; data stable post-flag so no atomicity needed.
    {
      const char* srcb = (const char*)(hbuf + (size_t)(s & 1) * (B_ * H_)
                                            + (size_t)(q * 16 + v * 4) * H_);
      u32x4 stg[8];
#pragma unroll
      for (int i = 0; i < 4; ++i)
#pragma unroll
        for (int j = 0; j < 2; ++j)
          asm volatile("global_load_dwordx4 %0, %1, off sc0 sc1"
                       : "=v"(stg[i * 2 + j])
                       : "v"(srcb + (size_t)i * 2048 + (j * 64 + lane) * 16)
                       : "memory");
      asm volatile("s_waitcnt vmcnt(0)"
                   : "+v"(stg[0]), "+v"(stg[1]), "+v"(stg[2]), "+v"(stg[3]),
                     "+v"(stg[4]), "+v"(stg[5]), "+v"(stg[6]), "+v"(stg[7])
                   :: "memory");
      __builtin_amdgcn_sched_barrier(0);
#pragma unroll
      for (int i = 0; i < 4; ++i) {
        const int r = v * 4 + i;
#pragma unroll
        for (int j = 0; j < 2; ++j) {
          const int u = j * 64 + lane;
          *(u32x4*)((char*)hs + (size_t)r * 2048 + ((u * 16) ^ ((r & 7) << 4))) =
              stg[i * 2 + j];
        }
      }
    }
    __syncthreads();   // barrier #1: stage visible to all waves

    // GEMV: acc[r] accumulates gate r at (row, col); 32 MFMAs, 4-way ILP
    f32x4 acc[4] = {};
#pragma unroll
    for (int kt = 0; kt < 32; ++kt) {
      bf16x8 bv = *(const bf16x8*)(hsb + l16 * 2048 + ((kt * 64 + quad * 16) ^ swz));
      acc[kt & 3] = __builtin_amdgcn_mfma_f32_16x16x32_bf16(wf[kt], bv, acc[kt & 3], 0, 0, 0);
    }

    f32x4 g4;
#pragma unroll
    for (int r = 0; r < 4; ++r)
      g4[r] = acc[0][r] + acc[1][r] + acc[2][r] + acc[3][r]
            + bias[r] + bf2f(gx4[r]);

    float iv = 1.f / (1.f + __expf(-g4[0]));
    float fv = 1.f / (1.f + __expf(-g4[1]));
    float gz = fminf(fmaxf(g4[2], -15.f), 15.f);
    float eg = __expf(2.f * gz);
    float gv = (eg - 1.f) / (eg + 1.f);
    float ov = 1.f / (1.f + __expf(-g4[3]));
    float cn = fv * cst + iv * gv;
    cst = cn;
    float cc = fminf(fmaxf(cn, -15.f), 15.f);
    float ec = __expf(2.f * cc);
    hl = ov * ((ec - 1.f) / (ec + 1.f));

    // pack h (bf16 x4 -> u64) and out (f32x4) into quad0 lanes
    float ha = __shfl_down(hl, 16);                  // col+1
    unsigned lo = (unsigned)f2bf(hl) | ((unsigned)f2bf(ha) << 16);
    unsigned p2 = __shfl_down(lo, 32);               // cols +2,+3
    float o2 = __shfl_down(hl, 32);                  // col+2
    float o3 = __shfl_down(ha, 32);                  // col+3

    if (quad == 0) {
      u64 pp = (u64)lo | ((u64)p2 << 32);
      __hip_atomic_store(
          (u64*)(hbuf + (size_t)((s + 1) & 1) * (B_ * H_)
                      + (size_t)row * H_ + colbase),
          pp, __ATOMIC_RELAXED, __HIP_MEMORY_SCOPE_AGENT);
    }
    __syncthreads();   // barrier #2: drains all waves' h stores; protects hs
    if (tid == 0)
      __hip_atomic_store(&flags[q * 64 + cg4], (unsigned)(s + 2),
                         __ATOMIC_RELAXED, __HIP_MEMORY_SCOPE_AGENT);
    // out store AFTER flag: off the cross-block critical path, coalesced 16B
    if (quad == 0) {
      f32x4 ovv = { hl, ha, o2, o3 };
      __builtin_nontemporal_store(ovv,
          (f32x4*)(out + ((size_t)row * S_ + s) * H_ + colbase));
    }
  }

  // final hN, cN
  {
    const size_t base = (size_t)B_ * S_ * H_;
    out[base + (size_t)row * H_ + col] = hl;
    out[base + (size_t)B_ * H_ + (size_t)row * H_ + col] = cst;
  }
}

// ---- launch ----------------------------------------------------------------
extern "C" void kernel_launch(void* const* d_in, const int* in_sizes, int n_in,
                              void* d_out, int out_size, void* d_ws, size_t ws_size,
                              hipStream_t stream) {
  const float* x  = (const float*)d_in[0];
  const float* h0 = (const float*)d_in[1];
  const float* c0 = (const float*)d_in[2];
  const float* wi = (const float*)d_in[3];
  const float* wh = (const float*)d_in[4];
  const float* bi = (const float*)d_in[5];
  const float* bh = (const float*)d_in[6];
  float* out = (float*)d_out;

  char* ws = (char*)d_ws;
  u16* xb   = (u16*)(ws);                   //  33,554,432 B (dead after gemm_bt)
  u16* wib  = (u16*)(ws + 33554432);        //   8,388,608 B (permuted W_i)
  u16* whb  = (u16*)(ws + 41943040);        //   8,388,608 B
  u16* gxp  = (u16*)(ws + 50331648);        // 134,217,728 B
  u16* hbuf = (u16*)(ws + 184549376);       //     262,144 B (double buffer)
  u32* flags = (u32*)(ws + 184811520);      //       1,024 B

  cvt_x<<<M_, 256, 0, stream>>>(x, xb);
  cvt_w_perm<<<NG, 256, 0, stream>>>(wi, wib);
  cvt_w<<<4096, 256, 0, stream>>>(wh, whb);
  gemm_bt<<<dim3(NG / 128, M_ / 128), 256, 0, stream>>>(xb, wib, gxp);
  // zero flags AFTER gemm_bt (stream-ordered): kills stale values on replay
  (void)hipMemsetAsync(flags, 0, 1024, stream);

  void* args[] = { &whb, &gxp, &bi, &bh, &h0, &c0, &hbuf, &flags, &out };
  (void)hipLaunchCooperativeKernel((void*)lstm_rec, dim3(256), dim3(256), args, 0, stream);
}